// Round 1
// baseline (336.491 us; speedup 1.0000x reference)
//
#include <hip/hip_runtime.h>

// DWT1D: x[32,64,16384] f32 -> out[32,192,8194] f32
// out channels: [0:64) = linear downsample of x to L, [64:128) = bior2.2 approx,
// [128:192) = bior2.2 detail (pywt symmetric mode).
//
// a[k] = sum_{m=1..5} LO[m] * x[sym(2k+1-m)], d[k] = sum_{m=1..3} HI[m]*x[sym(2k+1-m)]
// sym(j) = -j-1 (j<0), 2N-1-j (j>=N). Memory-bound: ~134 MB read + ~201 MB write.

namespace {
constexpr int kN = 16384;   // input row length
constexpr int kL = 8194;    // output row length = (N + 6 - 1) / 2
constexpr int kC = 64;      // channels
constexpr int kRows = 32 * kC;

__device__ __forceinline__ int symi(int j) {
    j = (j < 0) ? (-j - 1) : j;
    j = (j >= kN) ? (2 * kN - 1 - j) : j;
    return j;
}

__global__ __launch_bounds__(256) void dwt1d_kernel(const float* __restrict__ x,
                                                    float* __restrict__ out) {
    const int k = blockIdx.x * blockDim.x + threadIdx.x;
    const int row = blockIdx.y;                 // = b*64 + c
    if (k >= kL) return;

    const float* __restrict__ xr = x + (size_t)row * kN;

    // bior2.2 decomposition filters (nonzero taps)
    const float LO1 = -0.1767766952966369f;     // == LO5
    const float LO2 = 0.3535533905932738f;      // == LO4
    const float LO3 = 1.0606601717798212f;
    const float HI1 = 0.3535533905932738f;      // == HI3
    const float HI2 = -0.7071067811865476f;

    // v0..v4 = x[sym(2k-4)] .. x[sym(2k)]
    float v0, v1, v2, v3, v4;
    if (k >= 2 && k <= (kN / 2 - 1)) {
        // interior fast path: 2k-4 >= 0 and 2k+1 <= N-1; (2k-4) is even -> 8B aligned
        const float2* p = (const float2*)(xr + 2 * k - 4);
        float2 a0 = p[0];
        float2 a1 = p[1];
        float2 a2 = p[2];
        v0 = a0.x; v1 = a0.y; v2 = a1.x; v3 = a1.y; v4 = a2.x;
    } else {
        const int t = 2 * k;
        v0 = xr[symi(t - 4)];
        v1 = xr[symi(t - 3)];
        v2 = xr[symi(t - 2)];
        v3 = xr[symi(t - 1)];
        v4 = xr[symi(t)];
    }

    const float a = LO3 * v2 + LO2 * (v1 + v3) + LO1 * (v0 + v4);
    const float d = HI2 * v3 + HI1 * (v2 + v4);

    // linear interp, align_corners=False, N=16384 -> L=8194
    const float scale = 16384.0f / 8194.0f;
    float src = (k + 0.5f) * scale - 0.5f;
    src = fminf(fmaxf(src, 0.0f), (float)(kN - 1));
    int i0 = (int)floorf(src);
    int i1 = min(i0 + 1, kN - 1);
    float w = src - (float)i0;
    const float ds = xr[i0] * (1.0f - w) + xr[i1] * w;

    const int b = row >> 6;
    const int c = row & (kC - 1);
    const size_t base = ((size_t)(b * 192 + c)) * kL + k;
    out[base] = ds;                          // downsample plane
    out[base + (size_t)64 * kL] = a;         // approx plane
    out[base + (size_t)128 * kL] = d;        // detail plane
}
}  // namespace

extern "C" void kernel_launch(void* const* d_in, const int* in_sizes, int n_in,
                              void* d_out, int out_size, void* d_ws, size_t ws_size,
                              hipStream_t stream) {
    const float* x = (const float*)d_in[0];
    float* out = (float*)d_out;
    dim3 grid((kL + 255) / 256, kRows);
    dwt1d_kernel<<<grid, dim3(256), 0, stream>>>(x, out);
}

// Round 2
// 295.372 us; speedup vs baseline: 1.1392x; 1.1392x over previous
//
#include <hip/hip_runtime.h>

// DWT1D: x[32,64,16384] f32 -> out[32,192,8194] f32
// Planes: [0:64)=linear downsample, [64:128)=bior2.2 approx, [128:192)=detail.
//
// R2: LDS-staged tile version. Block = (tile,row); stages x[2k0-8 .. 2k0+4095]
// into LDS via coalesced float4 (symmetric mirror applied during staging),
// then 256 threads x 8 outputs each, all global stores wave-coalesced.
// R1 was latency-bound (27% HBM, 14% VALU): too little work per wave.

namespace {
constexpr int kN = 16384;   // input row length
constexpr int kL = 8194;    // output row length = (N + 6 - 1) / 2
constexpr int kTPB = 256;
constexpr int kOutPerThread = 8;
constexpr int kTile = kTPB * kOutPerThread;   // 2048 outputs per block
constexpr int kStage = 2 * kTile + 8;         // 4104 floats = 16416 B LDS

__device__ __forceinline__ int symi(int j) {
    j = (j < 0) ? (-j - 1) : j;
    j = (j >= kN) ? (2 * kN - 1 - j) : j;
    return j;
}

__global__ __launch_bounds__(256) void dwt1d_kernel(const float* __restrict__ x,
                                                    float* __restrict__ out) {
    __shared__ float s[kStage];

    const int tile = blockIdx.x;
    const int row  = blockIdx.y;                // b*64 + c
    const int tid  = threadIdx.x;
    const int k0   = tile * kTile;
    const int s0   = 2 * k0 - 8;                // first staged global index (16B-aligned)
    const int lastk = min(kL - 1, k0 + kTile - 1);
    const int cnt  = 2 * lastk - s0 + 1;        // staged floats actually needed
    const int nchunk = (cnt + 3) >> 2;

    const float* __restrict__ xr = x + (size_t)row * kN;

    // ---- stage global -> LDS (mirror applied for out-of-range indices) ----
    for (int cck = tid; cck < nchunk; cck += kTPB) {
        const int g = s0 + 4 * cck;
        float4 v;
        if (g >= 0 && g + 3 < kN) {
            v = *(const float4*)(xr + g);       // s0 % 4 == 0 -> 16B aligned
        } else {
            v.x = xr[symi(g)];
            v.y = xr[symi(g + 1)];
            v.z = xr[symi(g + 2)];
            v.w = xr[symi(g + 3)];
        }
        *(float4*)(s + 4 * cck) = v;
    }
    __syncthreads();

    // bior2.2 decomposition filters (nonzero taps; symmetric)
    const float LO1 = -0.1767766952966369f;
    const float LO2 = 0.3535533905932738f;
    const float LO3 = 1.0606601717798212f;
    const float HI1 = 0.3535533905932738f;
    const float HI2 = -0.7071067811865476f;
    const float scale = 16384.0f / 8194.0f;

    const int b = row >> 6;
    const int c = row & 63;
    float* __restrict__ o0 = out + ((size_t)(b * 192 + c)) * kL;  // downsample plane
    float* __restrict__ o1 = o0 + (size_t)64 * kL;                // approx plane
    float* __restrict__ o2 = o0 + (size_t)128 * kL;               // detail plane

#pragma unroll
    for (int j = 0; j < kOutPerThread; ++j) {
        const int kk = k0 + j * kTPB + tid;
        if (kk >= kL) continue;                 // only the last (tiny) tile diverges
        const int m = 2 * (kk - k0) + 8;        // LDS index of x[2k]

        // v0..v4 = x[sym(2k-4 .. 2k)]; m even -> 8B-aligned float2 reads
        const float2 q0 = *(const float2*)(s + m - 4);
        const float2 q1 = *(const float2*)(s + m - 2);
        const float v4 = s[m];
        const float a = LO3 * q1.x + LO2 * (q0.y + q1.y) + LO1 * (q0.x + v4);
        const float d = HI2 * q1.y + HI1 * (q1.x + v4);

        // linear interp, align_corners=False (i0 in [2k-5, 2k] -> in LDS)
        float src = (kk + 0.5f) * scale - 0.5f;
        src = fminf(fmaxf(src, 0.0f), (float)(kN - 1));
        const int i0 = (int)floorf(src);
        const int i1 = min(i0 + 1, kN - 1);
        const float w = src - (float)i0;
        const float ds = s[i0 - s0] * (1.0f - w) + s[i1 - s0] * w;

        o0[kk] = ds;
        o1[kk] = a;
        o2[kk] = d;
    }
}
}  // namespace

extern "C" void kernel_launch(void* const* d_in, const int* in_sizes, int n_in,
                              void* d_out, int out_size, void* d_ws, size_t ws_size,
                              hipStream_t stream) {
    const float* x = (const float*)d_in[0];
    float* out = (float*)d_out;
    dim3 grid((kL + kTile - 1) / kTile, 32 * 64);   // 5 x 2048 blocks
    dwt1d_kernel<<<grid, dim3(kTPB), 0, stream>>>(x, out);
}